// Round 12
// baseline (276.416 us; speedup 1.0000x reference)
//
#include <hip/hip_runtime.h>
#include <math.h>

#define D 128
#define MAXNORM 0.996f            // (1 - 4e-3)/sqrt(c), c = 1
#define MINNORM 1e-15f
#define ATCLAMP (1.0f - 1e-7f)

#define CHUNK 2048                // edges per sort block (8 per thread)
#define BSH   7                   // 128 nodes per bucket
#define MAXNB 1024                // supports N <= 131072 (problem: N = 100000)
#define SCAP3 5120                // kfin LDS sorted-record capacity (mean ~2046)

typedef unsigned int   u32;
typedef unsigned short u16;

typedef __attribute__((ext_vector_type(8))) _Float16 f16x8;
typedef __attribute__((ext_vector_type(2))) __fp16   h2raw;   // builtin return type
typedef __attribute__((ext_vector_type(4))) float f32x4;

__device__ __forceinline__ float wsum(float v) {
#pragma unroll
  for (int m = 32; m; m >>= 1) v += __shfl_xor(v, m);
  return v;
}
// 16-lane reduction (stays within a lane&48 group) — matches MFMA C-layout rows
__device__ __forceinline__ float rsum16(float v) {
#pragma unroll
  for (int m = 1; m <= 8; m <<= 1) v += __shfl_xor(v, m);
  return v;
}

__device__ __forceinline__ float frcp(float x) { return __builtin_amdgcn_rcpf(x); }

// fast artanh for x in [0, 1-1e-7]
__device__ __forceinline__ float fast_artanh(float x) {
  x = fminf(x, ATCLAMP);
  return 0.5f * __logf((1.0f + x) * frcp(1.0f - x));
}
// fast tanh for z >= 0
__device__ __forceinline__ float fast_tanh(float z) {
  float t = __expf(-2.0f * z);
  return (1.0f - t) * frcp(1.0f + t);
}

__device__ __forceinline__ float bflo(u32 u) { return __uint_as_float(u << 16); }
__device__ __forceinline__ float bfhi(u32 u) { return __uint_as_float(u & 0xffff0000u); }
__device__ __forceinline__ float bf2f(u16 h) { return __uint_as_float(((u32)h) << 16); }

// pack 2 f32 -> 2 f16 (RTZ, 1 instr v_cvt_pkrtz_f16_f32) — used for MFMA fragments
union H2U { h2raw h; u32 u; };
__device__ __forceinline__ u32 pkh(float a, float b) {
  H2U c; c.h = __builtin_amdgcn_cvt_pkrtz(a, b); return c.u;
}
union U2H { u32 u; _Float16 h[2]; };
union U4H8 { uint4 u; f16x8 h; };
__device__ __forceinline__ f16x8 as_h8(uint4 v) { U4H8 c; c.u = v; return c.h; }
__device__ __forceinline__ u16 f2h(float f) {        // f32 -> f16 bits (RNE)
  _Float16 h = (_Float16)f; return *(u16*)&h;
}

// ---- runtime dtype detection (wave-uniform; call before any divergence) ----
__device__ __forceinline__ bool detect_bf16(const u32* p) {
  float lo = fabsf(bflo(p[threadIdx.x & 63]));
  return (bool)__all(lo < 1.0f);
}
__device__ __forceinline__ bool detect_i64(const int* p) {
  return (bool)__all(p[2 * (threadIdx.x & 63) + 1] == 0);
}

// ====== K1 body: MFMA mobius_matvec + proj + mobius_add(bias) + proj + logmap0 ======
// FP16 compute plane (r8/9), permuted xt store (r9), one-tile-per-wave exit-and-
// refill launch (r10). 32 KB LDS single W plane.
// C layout (m89-verified): col = lane&15, row = (lane>>4)*4 + reg.
// xt layout: true col c at u16 position (c&15)*8 + (c>>4) -> one uint4/lane/row.
template<bool BF>
__device__ __forceinline__ void k1_body(const void* xv, const void* Wv,
                                        const void* bv, u16* xt, int N,
                                        uint4* Wh) {
  const int tid  = threadIdx.x;
  const int lane = tid & 63;
  const int wid  = tid >> 6;
  const int qg   = lane >> 4;   // k-block group 0..3
  const int lc   = lane & 15;   // col within 16-wide tile

  for (int slot = tid; slot < 2048; slot += 256) {
    const int l = slot & 63, frag = slot >> 6;
    const int t = frag >> 2, ks = frag & 3;
    const int j  = (l & 15) + 16 * t;
    const int k0 = 32 * ks + 8 * (l >> 4);
    float f[8];
    if (BF) {
      uint4 v = ((const uint4*)Wv)[j * 16 + (k0 >> 3)];
      f[0] = bflo(v.x); f[1] = bfhi(v.x); f[2] = bflo(v.y); f[3] = bfhi(v.y);
      f[4] = bflo(v.z); f[5] = bfhi(v.z); f[6] = bflo(v.w); f[7] = bfhi(v.w);
    } else {
      const float* Wf = (const float*)Wv;
      float4 f0 = *(const float4*)(Wf + (size_t)j * D + k0);
      float4 f1 = *(const float4*)(Wf + (size_t)j * D + k0 + 4);
      f[0]=f0.x; f[1]=f0.y; f[2]=f0.z; f[3]=f0.w;
      f[4]=f1.x; f[5]=f1.y; f[6]=f1.z; f[7]=f1.w;
    }
    Wh[slot] = make_uint4(pkh(f[0],f[1]), pkh(f[2],f[3]),
                          pkh(f[4],f[5]), pkh(f[6],f[7]));
  }

  // hyp_bias fragment: bfr[t] = proj(expmap0(b))[lc + 16t]
  float bfr[8];
  float nb2 = 0.f;
#pragma unroll
  for (int t = 0; t < 8; ++t) {
    float v = BF ? bf2f(((const u16*)bv)[lc + 16 * t])
                 : ((const float*)bv)[lc + 16 * t];
    bfr[t] = v; nb2 += v * v;
  }
  nb2 = rsum16(nb2);
  float y2;
  {
    float nb = fmaxf(sqrtf(nb2), MINNORM);
    float s  = fast_tanh(nb) * frcp(nb);
    float n1 = s * nb;
    if (n1 > MAXNORM) s *= MAXNORM * frcp(n1);
#pragma unroll
    for (int t = 0; t < 8; ++t) bfr[t] *= s;
    y2 = s * s * nb2;
  }
  const bool bias_zero = (y2 == 0.0f);

  __syncthreads();

  const int T = (N + 15) >> 4;
  const int tile = blockIdx.x * 4 + wid;      // ONE tile per wave
  if (tile >= T) return;
  {
    const int rbase = tile * 16;
    int rowA = rbase + lc; if (rowA >= N) rowA = N - 1;
    uint4 Ah[4];
    float xn2 = 0.f;
#pragma unroll
    for (int ks = 0; ks < 4; ++ks) {
      float f[8];
      if (BF) {
        uint4 v = ((const uint4*)((const u16*)xv + (size_t)rowA * D))[4 * ks + qg];
        f[0]=bflo(v.x); f[1]=bfhi(v.x); f[2]=bflo(v.y); f[3]=bfhi(v.y);
        f[4]=bflo(v.z); f[5]=bfhi(v.z); f[6]=bflo(v.w); f[7]=bfhi(v.w);
      } else {
        const float4* xr = (const float4*)((const float*)xv + (size_t)rowA * D);
        float4 f0 = xr[8 * ks + 2 * qg], f1 = xr[8 * ks + 2 * qg + 1];
        f[0]=f0.x; f[1]=f0.y; f[2]=f0.z; f[3]=f0.w;
        f[4]=f1.x; f[5]=f1.y; f[6]=f1.z; f[7]=f1.w;
      }
#pragma unroll
      for (int i = 0; i < 8; ++i) xn2 += f[i] * f[i];
      Ah[ks] = make_uint4(pkh(f[0],f[1]), pkh(f[2],f[3]),
                          pkh(f[4],f[5]), pkh(f[6],f[7]));
    }
    xn2 += __shfl_xor(xn2, 16);
    xn2 += __shfl_xor(xn2, 32);   // lane r holds ||x[rbase+r]||^2 (r = lane&15)

    f32x4 acc[8];
    const f32x4 zero = {0.f, 0.f, 0.f, 0.f};
#pragma unroll
    for (int t = 0; t < 8; ++t) acc[t] = zero;
#pragma unroll
    for (int ks = 0; ks < 4; ++ks) {
      f16x8 a = as_h8(Ah[ks]);
#pragma unroll
      for (int t = 0; t < 8; ++t) {
        f16x8 bh = as_h8(Wh[(t * 4 + ks) * 64 + lane]);
        acc[t] = __builtin_amdgcn_mfma_f32_16x16x32_f16(a, bh, acc[t], 0, 0, 0);
      }
    }

#pragma unroll
    for (int q = 0; q < 4; ++q) {
      const int row_off = qg * 4 + q;
      const int row = rbase + row_off;
      float xnq = fmaxf(sqrtf(__shfl(xn2, row_off)), MINNORM);
      float s2 = 0.f;
#pragma unroll
      for (int t = 0; t < 8; ++t) { float v = acc[t][q]; s2 += v * v; }
      s2 = rsum16(s2);
      float mxn = fmaxf(sqrtf(s2), MINNORM);
      float r = fast_tanh(mxn * frcp(xnq) * fast_artanh(xnq)) * frcp(mxn);
      float pn = r * mxn;
      if (pn > MAXNORM) { r *= MAXNORM * frcp(pn); pn = MAXNORM; }
      float h[8];
      float hn;
      if (bias_zero) {
#pragma unroll
        for (int t = 0; t < 8; ++t) h[t] = r * acc[t][q];
        hn = pn;
      } else {
        float xy = 0.f;
#pragma unroll
        for (int t = 0; t < 8; ++t) { h[t] = r * acc[t][q]; xy += h[t] * bfr[t]; }
        xy = rsum16(xy);
        float x2 = pn * pn;
        float ca = 1.f + 2.f * xy + y2;
        float cb = 1.f - x2;
        float id = frcp(fmaxf(1.f + 2.f * xy + x2 * y2, MINNORM));
        float s3 = 0.f;
#pragma unroll
        for (int t = 0; t < 8; ++t) { h[t] = (ca * h[t] + cb * bfr[t]) * id; s3 += h[t] * h[t]; }
        hn = fmaxf(sqrtf(rsum16(s3)), MINNORM);
      }
      float ps = (hn > MAXNORM) ? (MAXNORM * frcp(hn)) : 1.f;
      float np = fmaxf(hn * ps, MINNORM);
      float tsc = fast_artanh(np) * frcp(np) * ps;
      if (row < N) {
        // permuted store: positions lc*8..lc*8+7 = cols lc+16t, ONE uint4
        uint4 pk;
        pk.x = (u32)f2h(tsc * h[0]) | ((u32)f2h(tsc * h[1]) << 16);
        pk.y = (u32)f2h(tsc * h[2]) | ((u32)f2h(tsc * h[3]) << 16);
        pk.z = (u32)f2h(tsc * h[4]) | ((u32)f2h(tsc * h[5]) << 16);
        pk.w = (u32)f2h(tsc * h[6]) | ((u32)f2h(tsc * h[7]) << 16);
        *(uint4*)(xt + (size_t)row * D + lc * 8) = pk;
      }
    }
  }
}

// ====== ksA body: chunk-local counting sort -> chunk-major ebuck + soffs ======
// LDS aliased into the K1 W-plane (25.6 KB of 32 KB): recs | hist | sArr | psum.
// Record: x = src(17b)|dstin(7b)<<17, y = w bits.
__device__ __forceinline__ void ksA_body(
    const int* ei, const void* ew, uint2* ebuck, u16* soffs,
    int E, int N, int nb, int chunk, uint4* lds) {
  uint2* recs = (uint2*)lds;                 // 16 KB
  int*   hist = (int*)(lds + 1024);          // 4 KB
  int*   sArr = hist + MAXNB;                // 4.1 KB
  int*   psum = sArr + MAXNB + 1;            // 1 KB
  const bool i64 = detect_i64(ei);
  const bool bf  = detect_bf16((const u32*)ew);
  const int tid   = threadIdx.x;
  const int cbase = chunk * CHUNK;

  for (int i = tid; i < MAXNB; i += 256) hist[i] = 0;
  __syncthreads();

  int bkt[8], rank[8]; u32 px[8], wb[8]; bool val[8];
#pragma unroll
  for (int r = 0; r < 8; ++r) {
    const int e = cbase + r * 256 + tid;
    val[r] = false;
    if (e < E) {
      int dst, src;
      if (i64) {
        dst = (int)((const uint2*)ei)[(size_t)e].x;
        src = (int)((const uint2*)ei)[(size_t)E + e].x;
      } else {
        dst = ei[e]; src = ei[(size_t)E + e];
      }
      if ((unsigned)dst < (unsigned)N && (unsigned)src < (unsigned)N) {
        val[r] = true;
        bkt[r] = dst >> BSH;
        px[r]  = (u32)src | ((u32)(dst & ((1 << BSH) - 1)) << 17);
        float w;
        if (bf) w = bf2f(((const u16*)ew)[e]); else w = ((const float*)ew)[e];
        wb[r] = __float_as_uint(w);
        rank[r] = atomicAdd(&hist[bkt[r]], 1);
      }
    }
  }
  __syncthreads();

  // exclusive scan of hist -> sArr (256 threads x 4 bins)
  const int g0 = tid * 4;
  int loc[4], ts = 0;
#pragma unroll
  for (int i = 0; i < 4; ++i) { loc[i] = ts; ts += hist[g0 + i]; }
  psum[tid] = ts; __syncthreads();
#pragma unroll
  for (int off = 1; off < 256; off <<= 1) {
    int t = (tid >= off) ? psum[tid - off] : 0;
    __syncthreads();
    psum[tid] += t;
    __syncthreads();
  }
  const int excl = psum[tid] - ts;
#pragma unroll
  for (int i = 0; i < 4; ++i) sArr[g0 + i] = excl + loc[i];
  if (tid == 255) sArr[MAXNB] = psum[255];
  __syncthreads();

#pragma unroll
  for (int r = 0; r < 8; ++r) if (val[r])
    recs[sArr[bkt[r]] + rank[r]] = make_uint2(px[r], wb[r]);
  __syncthreads();

  const int vcnt = sArr[MAXNB];
  for (int i = tid; i < vcnt; i += 256) ebuck[(size_t)cbase + i] = recs[i];
  u16* so = soffs + (size_t)chunk * (nb + 1);
  for (int b = tid; b <= nb; b += 256) so[b] = (u16)sArr[b];
}

// ====== fused K1 + ksA: independent stages share one dispatch (r11 verified) ======
extern "C" __global__ __launch_bounds__(256)
void OriginHyperbolicGraphConvolution_38628935860614_kernel(
    const void* x, const void* W, const void* b, u16* xt,
    const int* ei, const void* ew, uint2* ebuck, u16* soffs,
    int N, int E, int nb, int nk1) {
  __shared__ uint4 Wh[2048];   // 32 KB: K1 W-plane / ksA sort buffers (aliased)
  if ((int)blockIdx.x < nk1) {
    if (detect_bf16((const u32*)x)) k1_body<true >(x, W, b, xt, N, Wh);
    else                            k1_body<false>(x, W, b, xt, N, Wh);
  } else {
    ksA_body(ei, ew, ebuck, soffs, E, N, nb, (int)blockIdx.x - nk1, Wh);
  }
}

// ---- shared finalize: expmap0 -> proj -> logmap0 -> relu -> expmap0 -> proj ----
// a0/a1 are PERMUTED positions 2*lane, 2*lane+1 (permutation-invariant math);
// final store unpermutes via 4 shfls (lane-verified in r9/r10).
__device__ __forceinline__ void finalize_store(
    float a0, float a1, int node, int lane, bool bf, void* out) {
  float n = fmaxf(sqrtf(wsum(a0 * a0 + a1 * a1)), MINNORM);
  float tn = fast_tanh(n);
  float m = tn * frcp(n);
  if (tn > MAXNORM) { m *= MAXNORM * frcp(tn); tn = MAXNORM; }
  float nn = fmaxf(tn, MINNORM);
  m *= fast_artanh(nn) * frcp(nn);
  float tA = fmaxf(m * a0, 0.f), tB = fmaxf(m * a1, 0.f);
  float nr = fmaxf(sqrtf(wsum(tA * tA + tB * tB)), MINNORM);
  float t2 = fast_tanh(nr);
  float m2 = t2 * frcp(nr);
  if (t2 > MAXNORM) m2 *= MAXNORM * frcp(t2);
  float oA = m2 * tA, oB = m2 * tB;
  const int ls = (lane & 7) * 8 + (lane >> 4);
  const int el = (lane >> 3) & 1;
  const float A0 = __shfl(oA, ls),     B0 = __shfl(oB, ls);
  const float A1 = __shfl(oA, ls + 4), B1 = __shfl(oB, ls + 4);
  const float v0 = el ? B0 : A0;
  const float v1 = el ? B1 : A1;
  if (bf) {
    u32 ua = __float_as_uint(v0), ub = __float_as_uint(v1);
    u32 ra = (ua + 0x7fffu + ((ua >> 16) & 1u)) >> 16;
    u32 rb = (ub + 0x7fffu + ((ub >> 16) & 1u)) >> 16;
    ((u32*)out)[(size_t)node * 64 + lane] = ra | (rb << 16);
  } else {
    ((float2*)out)[(size_t)node * 64 + lane] = make_float2(v0, v1);
  }
}

// ====== kfin: fused ks3 + kagg — sort bucket into LDS, aggregate from LDS ======
// Block per bucket, 512 threads (8 waves), 44 KB LDS -> 3 blocks/CU (24 w/CU).
// Phase A: walk soffs runs, per-node histogram + total count.
// Phase B: 128-scan -> per-node (start,count).
// Phase C: re-walk runs (L3-warm), scatter node-sorted into 40 KB LDS.
// Phase D: kagg inner loop verbatim, edge records via wave-uniform LDS reads
//          (broadcast); 16-deep gather ILP; register accumulate; finalize.
// esrt / offs2 / the 3rd launch are GONE. Fallback (cnt > SCAP3, ~0 prob on
// uniform data): streaming per-node scan over runs (correct for any skew).
extern "C" __global__ __launch_bounds__(512) void kfin(
    const uint2* ebuck, const u16* soffs, const u16* xt,
    void* out, const void* xdet, int N, int nb, int nchunks) {
  __shared__ uint2 srt[SCAP3];                    // 40 KB
  __shared__ int hist[128], nstart[128], cur[128], sc[128];
  __shared__ int redv[512];
  const bool bf = detect_bf16((const u32*)xdet);
  const int tid = threadIdx.x;
  const int lane = tid & 63, wid = tid >> 6;      // 8 waves
  const int b = blockIdx.x;
  const int node0 = b << BSH;
  const u32* xtw = (const u32*)xt;

  if (tid < 128) hist[tid] = 0;
  __syncthreads();

  // phase A: count + per-node histogram
  int myc = 0;
  for (int c = tid; c < nchunks; c += 512) {
    const u16* so = soffs + (size_t)c * (nb + 1) + b;
    const int a = so[0], e = so[1];
    myc += e - a;
    for (int j = a; j < e; ++j)
      atomicAdd(&hist[(ebuck[(size_t)c * CHUNK + j].x >> 17) & 127], 1);
  }
  redv[tid] = myc;
  __syncthreads();
#pragma unroll
  for (int off = 256; off; off >>= 1) {
    if (tid < off) redv[tid] += redv[tid + off];
    __syncthreads();
  }
  const int cnt = redv[0];

  // phase B: 128-scan -> nstart / cur
  int v = 0;
  if (tid < 128) { v = hist[tid]; sc[tid] = v; }
  __syncthreads();
#pragma unroll
  for (int off = 1; off < 128; off <<= 1) {
    int t = (tid < 128 && tid >= off) ? sc[tid - off] : 0;
    __syncthreads();
    if (tid < 128) sc[tid] += t;
    __syncthreads();
  }
  if (tid < 128) { nstart[tid] = sc[tid] - v; cur[tid] = sc[tid] - v; }
  __syncthreads();

  if (cnt <= SCAP3) {
    // phase C: scatter records node-sorted into LDS
    for (int c = tid; c < nchunks; c += 512) {
      const u16* so = soffs + (size_t)c * (nb + 1) + b;
      for (int j = so[0]; j < so[1]; ++j) {
        const uint2 r = ebuck[(size_t)c * CHUNK + j];
        const int d = atomicAdd(&cur[(r.x >> 17) & 127], 1);
        srt[d] = make_uint2(r.x & 0x1FFFFu, r.y);
      }
    }
    __syncthreads();

    // phase D: wave per node (interleaved), gather + accumulate + finalize
    for (int k = 0; k < 16; ++k) {
      const int nloc = wid + 8 * k;
      const int node = node0 + nloc;
      if (node >= N) continue;
      const int s0 = nstart[nloc];
      const int c2 = hist[nloc];
      float a0 = 0.f, a1 = 0.f;
      int i = 0;
      for (; i + 16 <= c2; i += 16) {
        uint2 e[16]; u32 u[16];
#pragma unroll
        for (int q = 0; q < 16; ++q) e[q] = srt[s0 + i + q];   // uniform LDS read
#pragma unroll
        for (int q = 0; q < 16; ++q) u[q] = xtw[(e[q].x << 6) | lane]; // 16 in flight
#pragma unroll
        for (int q = 0; q < 16; ++q) {
          const float w = __uint_as_float(e[q].y);
          U2H c; c.u = u[q];
          a0 += w * (float)c.h[0];
          a1 += w * (float)c.h[1];
        }
      }
      for (; i + 4 <= c2; i += 4) {
        uint2 e[4]; u32 u[4];
#pragma unroll
        for (int q = 0; q < 4; ++q) e[q] = srt[s0 + i + q];
#pragma unroll
        for (int q = 0; q < 4; ++q) u[q] = xtw[(e[q].x << 6) | lane];
#pragma unroll
        for (int q = 0; q < 4; ++q) {
          const float w = __uint_as_float(e[q].y);
          U2H c; c.u = u[q];
          a0 += w * (float)c.h[0];
          a1 += w * (float)c.h[1];
        }
      }
      for (; i < c2; ++i) {
        const uint2 e = srt[s0 + i];
        const u32 u = xtw[(e.x << 6) | lane];
        const float w = __uint_as_float(e.y);
        U2H c; c.u = u;
        a0 += w * (float)c.h[0];
        a1 += w * (float)c.h[1];
      }
      finalize_store(a0, a1, node, lane, bf, out);
    }
  } else {
    // fallback: streaming per-node scan over all runs (any skew; ~never hit)
    for (int k = 0; k < 16; ++k) {
      const int nloc = wid + 8 * k;
      const int node = node0 + nloc;
      if (node >= N) continue;
      float a0 = 0.f, a1 = 0.f;
      for (int c = 0; c < nchunks; ++c) {
        const u16* so = soffs + (size_t)c * (nb + 1) + b;
        const int a = so[0], e = so[1];
        for (int j = a; j < e; ++j) {
          const uint2 r = ebuck[(size_t)c * CHUNK + j];
          if ((int)((r.x >> 17) & 127) == nloc) {
            const u32 u = xtw[((r.x & 0x1FFFFu) << 6) | lane];
            const float w = __uint_as_float(r.y);
            U2H cc; cc.u = u;
            a0 += w * (float)cc.h[0];
            a1 += w * (float)cc.h[1];
          }
        }
      }
      finalize_store(a0, a1, node, lane, bf, out);
    }
  }
}

extern "C" void kernel_launch(void* const* d_in, const int* in_sizes, int n_in,
                              void* d_out, int out_size, void* d_ws, size_t ws_size,
                              hipStream_t stream) {
  const void* x    = d_in[0];
  const void* W    = d_in[1];
  const void* bias = d_in[2];
  const int*  ei   = (const int*)d_in[3];
  const void* ew   = d_in[4];
  const int N = in_sizes[0] / D;
  const int E = in_sizes[4];
  const int nchunks = (E + CHUNK - 1) / CHUNK;
  const int nb      = (N + (1 << BSH) - 1) >> BSH;

  char* ws = (char*)d_ws;
  size_t off = 0;
  auto carve = [&](size_t bytes) { char* p = ws + off; off = (off + bytes + 255) & ~(size_t)255; return p; };
  u16*   xt    = (u16*)  carve((size_t)N * D * sizeof(u16));                 // 25.6 MB
  uint2* ebuck = (uint2*)carve((size_t)nchunks * CHUNK * sizeof(uint2));     // 12.8 MB
  u16*   soffs = (u16*)  carve((size_t)nchunks * (nb + 1) * sizeof(u16));    // 1.2 MB

  const int T   = (N + 15) / 16;
  const int nk1 = (T + 3) / 4;    // K1 blocks (one tile per wave)

  OriginHyperbolicGraphConvolution_38628935860614_kernel<<<nk1 + nchunks, 256, 0, stream>>>(
      x, W, bias, xt, ei, ew, ebuck, soffs, N, E, nb, nk1);
  kfin<<<nb, 512, 0, stream>>>(ebuck, soffs, xt, d_out, x, N, nb, nchunks);
}

// Round 13
// 245.080 us; speedup vs baseline: 1.1279x; 1.1279x over previous
//
#include <hip/hip_runtime.h>
#include <math.h>

#define D 128
#define MAXNORM 0.996f            // (1 - 4e-3)/sqrt(c), c = 1
#define MINNORM 1e-15f
#define ATCLAMP (1.0f - 1e-7f)

#define CHUNK 2048                // edges per sort block (8 per thread)
#define BSH   7                   // 128 nodes per bucket
#define MAXNB 1024                // supports N <= 131072 (problem: N = 100000)
#define SCAP2 5120                // ks3 LDS staging records (mean ~2046/bucket)
#define CAP   4096                // fixed esrt slot per bucket (2x mean load)
#define TCAP  (1 << 20)           // tail region records (overflow spill)

typedef unsigned int   u32;
typedef unsigned short u16;

typedef __attribute__((ext_vector_type(8))) _Float16 f16x8;
typedef __attribute__((ext_vector_type(2))) __fp16   h2raw;   // builtin return type
typedef __attribute__((ext_vector_type(4))) float f32x4;

__device__ __forceinline__ float wsum(float v) {
#pragma unroll
  for (int m = 32; m; m >>= 1) v += __shfl_xor(v, m);
  return v;
}
// 16-lane reduction (stays within a lane&48 group) — matches MFMA C-layout rows
__device__ __forceinline__ float rsum16(float v) {
#pragma unroll
  for (int m = 1; m <= 8; m <<= 1) v += __shfl_xor(v, m);
  return v;
}

__device__ __forceinline__ float frcp(float x) { return __builtin_amdgcn_rcpf(x); }

// fast artanh for x in [0, 1-1e-7]
__device__ __forceinline__ float fast_artanh(float x) {
  x = fminf(x, ATCLAMP);
  return 0.5f * __logf((1.0f + x) * frcp(1.0f - x));
}
// fast tanh for z >= 0
__device__ __forceinline__ float fast_tanh(float z) {
  float t = __expf(-2.0f * z);
  return (1.0f - t) * frcp(1.0f + t);
}

__device__ __forceinline__ float bflo(u32 u) { return __uint_as_float(u << 16); }
__device__ __forceinline__ float bfhi(u32 u) { return __uint_as_float(u & 0xffff0000u); }
__device__ __forceinline__ float bf2f(u16 h) { return __uint_as_float(((u32)h) << 16); }

// pack 2 f32 -> 2 f16 (RTZ, 1 instr v_cvt_pkrtz_f16_f32) — used for MFMA fragments
union H2U { h2raw h; u32 u; };
__device__ __forceinline__ u32 pkh(float a, float b) {
  H2U c; c.h = __builtin_amdgcn_cvt_pkrtz(a, b); return c.u;
}
union U2H { u32 u; _Float16 h[2]; };
union U4H8 { uint4 u; f16x8 h; };
__device__ __forceinline__ f16x8 as_h8(uint4 v) { U4H8 c; c.u = v; return c.h; }
__device__ __forceinline__ u16 f2h(float f) {        // f32 -> f16 bits (RNE)
  _Float16 h = (_Float16)f; return *(u16*)&h;
}

// ---- runtime dtype detection (wave-uniform; call before any divergence) ----
__device__ __forceinline__ bool detect_bf16(const u32* p) {
  float lo = fabsf(bflo(p[threadIdx.x & 63]));
  return (bool)__all(lo < 1.0f);
}
__device__ __forceinline__ bool detect_i64(const int* p) {
  return (bool)__all(p[2 * (threadIdx.x & 63) + 1] == 0);
}

// ====== K1 body: MFMA mobius_matvec + proj + mobius_add(bias) + proj + logmap0 ======
// FP16 compute plane (r8/9), permuted xt store (r9), one-tile-per-wave exit-and-
// refill launch (r10). 32 KB LDS single W plane. NEW (r13): tile index takes a
// relative block id `blk` + tile base `tbase` so K1's tiles can be split across
// two dispatches (half overlaps ksA, half overlaps ks3).
// C layout (m89-verified): col = lane&15, row = (lane>>4)*4 + reg.
// xt layout: true col c at u16 position (c&15)*8 + (c>>4) -> one uint4/lane/row.
template<bool BF>
__device__ __forceinline__ void k1_body(const void* xv, const void* Wv,
                                        const void* bv, u16* xt, int N,
                                        uint4* Wh, int blk, int tbase) {
  const int tid  = threadIdx.x;
  const int lane = tid & 63;
  const int wid  = tid >> 6;
  const int qg   = lane >> 4;   // k-block group 0..3
  const int lc   = lane & 15;   // col within 16-wide tile

  for (int slot = tid; slot < 2048; slot += 256) {
    const int l = slot & 63, frag = slot >> 6;
    const int t = frag >> 2, ks = frag & 3;
    const int j  = (l & 15) + 16 * t;
    const int k0 = 32 * ks + 8 * (l >> 4);
    float f[8];
    if (BF) {
      uint4 v = ((const uint4*)Wv)[j * 16 + (k0 >> 3)];
      f[0] = bflo(v.x); f[1] = bfhi(v.x); f[2] = bflo(v.y); f[3] = bfhi(v.y);
      f[4] = bflo(v.z); f[5] = bfhi(v.z); f[6] = bflo(v.w); f[7] = bfhi(v.w);
    } else {
      const float* Wf = (const float*)Wv;
      float4 f0 = *(const float4*)(Wf + (size_t)j * D + k0);
      float4 f1 = *(const float4*)(Wf + (size_t)j * D + k0 + 4);
      f[0]=f0.x; f[1]=f0.y; f[2]=f0.z; f[3]=f0.w;
      f[4]=f1.x; f[5]=f1.y; f[6]=f1.z; f[7]=f1.w;
    }
    Wh[slot] = make_uint4(pkh(f[0],f[1]), pkh(f[2],f[3]),
                          pkh(f[4],f[5]), pkh(f[6],f[7]));
  }

  // hyp_bias fragment: bfr[t] = proj(expmap0(b))[lc + 16t]
  float bfr[8];
  float nb2 = 0.f;
#pragma unroll
  for (int t = 0; t < 8; ++t) {
    float v = BF ? bf2f(((const u16*)bv)[lc + 16 * t])
                 : ((const float*)bv)[lc + 16 * t];
    bfr[t] = v; nb2 += v * v;
  }
  nb2 = rsum16(nb2);
  float y2;
  {
    float nb = fmaxf(sqrtf(nb2), MINNORM);
    float s  = fast_tanh(nb) * frcp(nb);
    float n1 = s * nb;
    if (n1 > MAXNORM) s *= MAXNORM * frcp(n1);
#pragma unroll
    for (int t = 0; t < 8; ++t) bfr[t] *= s;
    y2 = s * s * nb2;
  }
  const bool bias_zero = (y2 == 0.0f);

  __syncthreads();

  const int T = (N + 15) >> 4;
  const int tile = tbase + blk * 4 + wid;     // ONE tile per wave
  if (tile >= T) return;
  {
    const int rbase = tile * 16;
    int rowA = rbase + lc; if (rowA >= N) rowA = N - 1;
    uint4 Ah[4];
    float xn2 = 0.f;
#pragma unroll
    for (int ks = 0; ks < 4; ++ks) {
      float f[8];
      if (BF) {
        uint4 v = ((const uint4*)((const u16*)xv + (size_t)rowA * D))[4 * ks + qg];
        f[0]=bflo(v.x); f[1]=bfhi(v.x); f[2]=bflo(v.y); f[3]=bfhi(v.y);
        f[4]=bflo(v.z); f[5]=bfhi(v.z); f[6]=bflo(v.w); f[7]=bfhi(v.w);
      } else {
        const float4* xr = (const float4*)((const float*)xv + (size_t)rowA * D);
        float4 f0 = xr[8 * ks + 2 * qg], f1 = xr[8 * ks + 2 * qg + 1];
        f[0]=f0.x; f[1]=f0.y; f[2]=f0.z; f[3]=f0.w;
        f[4]=f1.x; f[5]=f1.y; f[6]=f1.z; f[7]=f1.w;
      }
#pragma unroll
      for (int i = 0; i < 8; ++i) xn2 += f[i] * f[i];
      Ah[ks] = make_uint4(pkh(f[0],f[1]), pkh(f[2],f[3]),
                          pkh(f[4],f[5]), pkh(f[6],f[7]));
    }
    xn2 += __shfl_xor(xn2, 16);
    xn2 += __shfl_xor(xn2, 32);   // lane r holds ||x[rbase+r]||^2 (r = lane&15)

    f32x4 acc[8];
    const f32x4 zero = {0.f, 0.f, 0.f, 0.f};
#pragma unroll
    for (int t = 0; t < 8; ++t) acc[t] = zero;
#pragma unroll
    for (int ks = 0; ks < 4; ++ks) {
      f16x8 a = as_h8(Ah[ks]);
#pragma unroll
      for (int t = 0; t < 8; ++t) {
        f16x8 bh = as_h8(Wh[(t * 4 + ks) * 64 + lane]);
        acc[t] = __builtin_amdgcn_mfma_f32_16x16x32_f16(a, bh, acc[t], 0, 0, 0);
      }
    }

#pragma unroll
    for (int q = 0; q < 4; ++q) {
      const int row_off = qg * 4 + q;
      const int row = rbase + row_off;
      float xnq = fmaxf(sqrtf(__shfl(xn2, row_off)), MINNORM);
      float s2 = 0.f;
#pragma unroll
      for (int t = 0; t < 8; ++t) { float v = acc[t][q]; s2 += v * v; }
      s2 = rsum16(s2);
      float mxn = fmaxf(sqrtf(s2), MINNORM);
      float r = fast_tanh(mxn * frcp(xnq) * fast_artanh(xnq)) * frcp(mxn);
      float pn = r * mxn;
      if (pn > MAXNORM) { r *= MAXNORM * frcp(pn); pn = MAXNORM; }
      float h[8];
      float hn;
      if (bias_zero) {
#pragma unroll
        for (int t = 0; t < 8; ++t) h[t] = r * acc[t][q];
        hn = pn;
      } else {
        float xy = 0.f;
#pragma unroll
        for (int t = 0; t < 8; ++t) { h[t] = r * acc[t][q]; xy += h[t] * bfr[t]; }
        xy = rsum16(xy);
        float x2 = pn * pn;
        float ca = 1.f + 2.f * xy + y2;
        float cb = 1.f - x2;
        float id = frcp(fmaxf(1.f + 2.f * xy + x2 * y2, MINNORM));
        float s3 = 0.f;
#pragma unroll
        for (int t = 0; t < 8; ++t) { h[t] = (ca * h[t] + cb * bfr[t]) * id; s3 += h[t] * h[t]; }
        hn = fmaxf(sqrtf(rsum16(s3)), MINNORM);
      }
      float ps = (hn > MAXNORM) ? (MAXNORM * frcp(hn)) : 1.f;
      float np = fmaxf(hn * ps, MINNORM);
      float tsc = fast_artanh(np) * frcp(np) * ps;
      if (row < N) {
        // permuted store: positions lc*8..lc*8+7 = cols lc+16t, ONE uint4
        uint4 pk;
        pk.x = (u32)f2h(tsc * h[0]) | ((u32)f2h(tsc * h[1]) << 16);
        pk.y = (u32)f2h(tsc * h[2]) | ((u32)f2h(tsc * h[3]) << 16);
        pk.z = (u32)f2h(tsc * h[4]) | ((u32)f2h(tsc * h[5]) << 16);
        pk.w = (u32)f2h(tsc * h[6]) | ((u32)f2h(tsc * h[7]) << 16);
        *(uint4*)(xt + (size_t)row * D + lc * 8) = pk;
      }
    }
  }
}

// ====== ksA body: chunk-local counting sort -> chunk-major ebuck + soffs ======
// LDS aliased into the K1 W-plane (25.6 KB of 32 KB): recs | hist | sArr | psum.
// Record: x = src(17b)|dstin(7b)<<17, y = w bits.
__device__ __forceinline__ void ksA_body(
    const int* ei, const void* ew, uint2* ebuck, u16* soffs,
    int E, int N, int nb, int chunk, uint4* lds) {
  uint2* recs = (uint2*)lds;                 // 16 KB
  int*   hist = (int*)(lds + 1024);          // 4 KB
  int*   sArr = hist + MAXNB;                // 4.1 KB
  int*   psum = sArr + MAXNB + 1;            // 1 KB
  const bool i64 = detect_i64(ei);
  const bool bf  = detect_bf16((const u32*)ew);
  const int tid   = threadIdx.x;
  const int cbase = chunk * CHUNK;

  for (int i = tid; i < MAXNB; i += 256) hist[i] = 0;
  __syncthreads();

  int bkt[8], rank[8]; u32 px[8], wb[8]; bool val[8];
#pragma unroll
  for (int r = 0; r < 8; ++r) {
    const int e = cbase + r * 256 + tid;
    val[r] = false;
    if (e < E) {
      int dst, src;
      if (i64) {
        dst = (int)((const uint2*)ei)[(size_t)e].x;
        src = (int)((const uint2*)ei)[(size_t)E + e].x;
      } else {
        dst = ei[e]; src = ei[(size_t)E + e];
      }
      if ((unsigned)dst < (unsigned)N && (unsigned)src < (unsigned)N) {
        val[r] = true;
        bkt[r] = dst >> BSH;
        px[r]  = (u32)src | ((u32)(dst & ((1 << BSH) - 1)) << 17);
        float w;
        if (bf) w = bf2f(((const u16*)ew)[e]); else w = ((const float*)ew)[e];
        wb[r] = __float_as_uint(w);
        rank[r] = atomicAdd(&hist[bkt[r]], 1);
      }
    }
  }
  __syncthreads();

  // exclusive scan of hist -> sArr (256 threads x 4 bins)
  const int g0 = tid * 4;
  int loc[4], ts = 0;
#pragma unroll
  for (int i = 0; i < 4; ++i) { loc[i] = ts; ts += hist[g0 + i]; }
  psum[tid] = ts; __syncthreads();
#pragma unroll
  for (int off = 1; off < 256; off <<= 1) {
    int t = (tid >= off) ? psum[tid - off] : 0;
    __syncthreads();
    psum[tid] += t;
    __syncthreads();
  }
  const int excl = psum[tid] - ts;
#pragma unroll
  for (int i = 0; i < 4; ++i) sArr[g0 + i] = excl + loc[i];
  if (tid == 255) sArr[MAXNB] = psum[255];
  __syncthreads();

#pragma unroll
  for (int r = 0; r < 8; ++r) if (val[r])
    recs[sArr[bkt[r]] + rank[r]] = make_uint2(px[r], wb[r]);
  __syncthreads();

  const int vcnt = sArr[MAXNB];
  for (int i = tid; i < vcnt; i += 256) ebuck[(size_t)cbase + i] = recs[i];
  u16* so = soffs + (size_t)chunk * (nb + 1);
  for (int b = tid; b <= nb; b += 256) so[b] = (u16)sArr[b];
}

// ====== dispatch 1: ksA (blocks [0,nchunks)) ∥ K1 part A (blocks [nchunks,..)) ======
extern "C" __global__ __launch_bounds__(256)
void OriginHyperbolicGraphConvolution_38628935860614_kernel(
    const void* x, const void* W, const void* b, u16* xt,
    const int* ei, const void* ew, uint2* ebuck, u16* soffs, int* tailcur,
    int N, int E, int nb, int nchunks) {
  __shared__ uint4 Wh[2048];   // 32 KB: K1 W-plane / ksA sort buffers (aliased)
  if (blockIdx.x == 0 && threadIdx.x == 0) *tailcur = 0;
  if ((int)blockIdx.x < nchunks) {
    ksA_body(ei, ew, ebuck, soffs, E, N, nb, (int)blockIdx.x, Wh);
  } else {
    if (detect_bf16((const u32*)x))
      k1_body<true >(x, W, b, xt, N, Wh, (int)blockIdx.x - nchunks, 0);
    else
      k1_body<false>(x, W, b, xt, N, Wh, (int)blockIdx.x - nchunks, 0);
  }
}

// ====== ks3 body: gather bucket's runs -> LDS -> node-sort -> esrt slot + offs2 ======
// (r11 verified.) Bucket b owns fixed slot [b*CAP, b*CAP+CAP) in esrt; pre-pass
// sums the soffs column for cnt; overflow claims tail via ONE atomic.
__device__ __forceinline__ void ks3_body(
    const uint2* ebuck, const u16* soffs, uint2* esrt, uint2* offs2,
    int* tailcur, int N, int nb, int nchunks, int b, char* smem) {
  uint2* stage = (uint2*)smem;                       // 40960 B
  int*   red   = (int*)(smem + 40960);               // 1024 B
  int*   hist  = (int*)(smem + 41984);               // 512 B
  int*   sc    = (int*)(smem + 42496);               // 512 B
  int*   cur   = (int*)(smem + 43008);               // 512 B
  int*   lcur  = (int*)(smem + 43520);
  u32*   sbase = (u32*)(smem + 43524);
  const int tid = threadIdx.x;
  const int node0 = b << BSH;

  // pre-pass: cnt = sum over chunks of this bucket's run lengths
  int myc = 0;
  for (int c = tid; c < nchunks; c += 256) {
    const u16* so = soffs + (size_t)c * (nb + 1) + b;
    myc += (int)so[1] - (int)so[0];
  }
  red[tid] = myc;
  if (tid < 128) hist[tid] = 0;
  if (tid == 0) *lcur = 0;
  __syncthreads();
#pragma unroll
  for (int off = 128; off; off >>= 1) {
    if (tid < off) red[tid] += red[tid + off];
    __syncthreads();
  }
  const int cnt = red[0];
  if (tid == 0)
    *sbase = (cnt <= CAP) ? (u32)((size_t)b * CAP)
                          : (u32)((size_t)nb * CAP + (u32)atomicAdd(tailcur, cnt));
  __syncthreads();
  const u32 base = *sbase;

  const bool fit = (cnt <= SCAP2);
  if (fit) {
    for (int c = tid; c < nchunks; c += 256) {
      const u16* so = soffs + (size_t)c * (nb + 1) + b;
      const int a = so[0], e = so[1];
      if (e > a) {
        const int sb = atomicAdd(lcur, e - a);
        for (int j = a; j < e; ++j) {
          const uint2 r = ebuck[(size_t)c * CHUNK + j];
          stage[sb + (j - a)] = r;
          atomicAdd(&hist[(r.x >> 17) & 127], 1);
        }
      }
    }
  } else {
    for (int c = tid; c < nchunks; c += 256) {
      const u16* so = soffs + (size_t)c * (nb + 1) + b;
      for (int j = so[0]; j < so[1]; ++j)
        atomicAdd(&hist[(ebuck[(size_t)c * CHUNK + j].x >> 17) & 127], 1);
    }
  }
  __syncthreads();

  int v = 0;
  if (tid < 128) { v = hist[tid]; sc[tid] = v; }
  __syncthreads();
#pragma unroll
  for (int off = 1; off < 128; off <<= 1) {
    int t = (tid < 128 && tid >= off) ? sc[tid - off] : 0;
    __syncthreads();
    if (tid < 128) sc[tid] += t;
    __syncthreads();
  }
  if (tid < 128) {
    const int st = sc[tid] - v;
    cur[tid] = st;
    const int node = node0 + tid;
    if (node < N) offs2[node] = make_uint2(base + (u32)st, (u32)v);
  }
  __syncthreads();

  if (fit) {
    for (int i = tid; i < cnt; i += 256) {
      const uint2 r = stage[i];
      const int d = atomicAdd(&cur[(r.x >> 17) & 127], 1);
      esrt[(size_t)base + d] = make_uint2(r.x & 0x1FFFFu, r.y);
    }
  } else {
    for (int c = tid; c < nchunks; c += 256) {
      const u16* so = soffs + (size_t)c * (nb + 1) + b;
      for (int j = so[0]; j < so[1]; ++j) {
        const uint2 r = ebuck[(size_t)c * CHUNK + j];
        const int d = atomicAdd(&cur[(r.x >> 17) & 127], 1);
        esrt[(size_t)base + d] = make_uint2(r.x & 0x1FFFFu, r.y);
      }
    }
  }
}

// ====== dispatch 2: ks3 (blocks [0,nb)) ∥ K1 part B (blocks [nb,..)) ======
// Shared LDS union: ks3 view (43.5 KB) / K1 W-plane (32 KB) -> 3 blocks/CU.
extern "C" __global__ __launch_bounds__(256) void kB(
    const void* x, const void* W, const void* b, u16* xt,
    const uint2* ebuck, const u16* soffs, uint2* esrt, uint2* offs2,
    int* tailcur, int N, int nb, int nchunks, int tbase) {
  __shared__ uint4 smem[2721];   // 43536 B union
  if ((int)blockIdx.x < nb) {
    ks3_body(ebuck, soffs, esrt, offs2, tailcur, N, nb, nchunks,
             (int)blockIdx.x, (char*)smem);
  } else {
    if (detect_bf16((const u32*)x))
      k1_body<true >(x, W, b, xt, N, smem, (int)blockIdx.x - nb, tbase);
    else
      k1_body<false>(x, W, b, xt, N, smem, (int)blockIdx.x - nb, tbase);
  }
}

// ====== kagg: gather-aggregate per node + fused finalize (r10/r11 verified) ======
// Wave per node, register accumulation, wave-uniform s_load edge records,
// 16-deep gather ILP. xt is fp16 PERMUTED (pos p = (c&15)*8 + (c>>4));
// accumulation + finalize are permutation-invariant; the final store
// unpermutes via 4 shfls (lane l needs true cols 2l, 2l+1).
extern "C" __global__ __launch_bounds__(256) void kagg(
    const uint2* offs2, const uint2* esrt, const u16* xt,
    void* out, const void* xdet, int N) {
  const bool bf = detect_bf16((const u32*)xdet);
  const int lane = threadIdx.x & 63;
  const int node = blockIdx.x * 4 + (threadIdx.x >> 6);
  if (node >= N) return;
  const uint2 oo = offs2[node];
  const int s0  = __builtin_amdgcn_readfirstlane((int)oo.x);
  const int cnt = __builtin_amdgcn_readfirstlane((int)oo.y);
  const uint2* ep = esrt + s0;
  const u32* xtw = (const u32*)xt;
  float a0 = 0.f, a1 = 0.f;      // permuted positions 2*lane, 2*lane+1
  int i = 0;
  for (; i + 16 <= cnt; i += 16) {
    uint2 e[16]; u32 u[16];
#pragma unroll
    for (int k = 0; k < 16; ++k) e[k] = ep[i + k];            // uniform (s_load)
#pragma unroll
    for (int k = 0; k < 16; ++k) u[k] = xtw[(e[k].x << 6) | lane];  // 16 in flight
#pragma unroll
    for (int k = 0; k < 16; ++k) {
      const float w = __uint_as_float(e[k].y);
      U2H c; c.u = u[k];
      a0 += w * (float)c.h[0];
      a1 += w * (float)c.h[1];
    }
  }
  for (; i + 4 <= cnt; i += 4) {
    uint2 e[4]; u32 u[4];
#pragma unroll
    for (int k = 0; k < 4; ++k) e[k] = ep[i + k];
#pragma unroll
    for (int k = 0; k < 4; ++k) u[k] = xtw[(e[k].x << 6) | lane];
#pragma unroll
    for (int k = 0; k < 4; ++k) {
      const float w = __uint_as_float(e[k].y);
      U2H c; c.u = u[k];
      a0 += w * (float)c.h[0];
      a1 += w * (float)c.h[1];
    }
  }
  for (; i < cnt; ++i) {
    const uint2 e = ep[i];
    const u32 u = xtw[(e.x << 6) | lane];
    const float w = __uint_as_float(e.y);
    U2H c; c.u = u;
    a0 += w * (float)c.h[0];
    a1 += w * (float)c.h[1];
  }
  // finalize: expmap0 -> proj -> logmap0 -> relu -> expmap0 -> proj
  float n = fmaxf(sqrtf(wsum(a0 * a0 + a1 * a1)), MINNORM);
  float tn = fast_tanh(n);
  float m = tn * frcp(n);
  if (tn > MAXNORM) { m *= MAXNORM * frcp(tn); tn = MAXNORM; }
  float nn = fmaxf(tn, MINNORM);
  m *= fast_artanh(nn) * frcp(nn);
  float tA = fmaxf(m * a0, 0.f), tB = fmaxf(m * a1, 0.f);
  float nr = fmaxf(sqrtf(wsum(tA * tA + tB * tB)), MINNORM);
  float t2 = fast_tanh(nr);
  float m2 = t2 * frcp(nr);
  if (t2 > MAXNORM) m2 *= MAXNORM * frcp(t2);
  float oA = m2 * tA, oB = m2 * tB;   // values for permuted positions 2l, 2l+1
  // unpermute: true col 2l lives at pos p0=(l&7)*16+(l>>3) -> lane p0>>1,
  // elem p0&1; true col 2l+1 at p0+8 -> lane+4, same elem. (lane-verified)
  const int ls = (lane & 7) * 8 + (lane >> 4);
  const int el = (lane >> 3) & 1;
  const float A0 = __shfl(oA, ls),     B0 = __shfl(oB, ls);
  const float A1 = __shfl(oA, ls + 4), B1 = __shfl(oB, ls + 4);
  const float v0 = el ? B0 : A0;
  const float v1 = el ? B1 : A1;
  if (bf) {
    u32 ua = __float_as_uint(v0), ub = __float_as_uint(v1);
    u32 ra = (ua + 0x7fffu + ((ua >> 16) & 1u)) >> 16;
    u32 rb = (ub + 0x7fffu + ((ub >> 16) & 1u)) >> 16;
    ((u32*)out)[(size_t)node * 64 + lane] = ra | (rb << 16);
  } else {
    ((float2*)out)[(size_t)node * 64 + lane] = make_float2(v0, v1);
  }
}

extern "C" void kernel_launch(void* const* d_in, const int* in_sizes, int n_in,
                              void* d_out, int out_size, void* d_ws, size_t ws_size,
                              hipStream_t stream) {
  const void* x    = d_in[0];
  const void* W    = d_in[1];
  const void* bias = d_in[2];
  const int*  ei   = (const int*)d_in[3];
  const void* ew   = d_in[4];
  const int N = in_sizes[0] / D;
  const int E = in_sizes[4];
  const int nchunks = (E + CHUNK - 1) / CHUNK;
  const int nb      = (N + (1 << BSH) - 1) >> BSH;

  char* ws = (char*)d_ws;
  size_t off = 0;
  auto carve = [&](size_t bytes) { char* p = ws + off; off = (off + bytes + 255) & ~(size_t)255; return p; };
  u16*   xt    = (u16*)  carve((size_t)N * D * sizeof(u16));                 // 25.6 MB
  uint2* ebuck = (uint2*)carve((size_t)nchunks * CHUNK * sizeof(uint2));     // 12.8 MB
  uint2* esrt  = (uint2*)carve(((size_t)nb * CAP + TCAP) * sizeof(uint2));   // 34 MB
  u16*   soffs = (u16*)  carve((size_t)nchunks * (nb + 1) * sizeof(u16));    // 1.2 MB
  uint2* offs2 = (uint2*)carve((size_t)N * sizeof(uint2));                   // 0.8 MB
  int*   tailcur = (int*)carve(256);

  const int T    = (N + 15) / 16;
  const int nk1  = (T + 3) / 4;        // total K1 blocks (one tile per wave)
  const int nk1a = nk1 / 2;            // K1 share in dispatch 1 (with ksA)
  const int nk1b = nk1 - nk1a;         // K1 share in dispatch 2 (with ks3)

  OriginHyperbolicGraphConvolution_38628935860614_kernel<<<nchunks + nk1a, 256, 0, stream>>>(
      x, W, bias, xt, ei, ew, ebuck, soffs, tailcur, N, E, nb, nchunks);
  kB<<<nb + nk1b, 256, 0, stream>>>(
      x, W, bias, xt, ebuck, soffs, esrt, offs2, tailcur, N, nb, nchunks, nk1a * 4);
  kagg<<<(N + 3) / 4, 256, 0, stream>>>(offs2, esrt, xt, d_out, x, N);
}